// Round 7
// baseline (460.528 us; speedup 1.0000x reference)
//
#include <hip/hip_runtime.h>
#include <hip/hip_bf16.h>
#include <cstdint>
#include <cstddef>

#define S_LEN 2048
#define D_MODEL 1024
#define N_HEADS 16
#define DEPTH 64
#define BATCH 4

#define GLOBAL_AS __attribute__((address_space(1)))
#define LDS_AS __attribute__((address_space(3)))

typedef __attribute__((ext_vector_type(4))) float f32x4;
typedef __attribute__((ext_vector_type(8))) short bf16x8;
typedef __attribute__((ext_vector_type(4))) unsigned short us4;
typedef __attribute__((ext_vector_type(8))) unsigned short us8;

__device__ __forceinline__ unsigned short f2bf(float f) {
  unsigned int u = __builtin_bit_cast(unsigned int, f);
  u += 0x7FFFu + ((u >> 16) & 1u);   // round-to-nearest-even
  return (unsigned short)(u >> 16);
}

// HW cast (compiler emits v_cvt_pk_bf16_f32 pairs)
__device__ __forceinline__ unsigned short f2bf_hw(float f) {
  return __builtin_bit_cast(unsigned short, __float2bfloat16(f));
}

// ---------------------------------------------------------------------------
// Weight transpose + scale + fp32 -> bf16 cast:  Wt[n][k] = W[k][n] * scale
// ---------------------------------------------------------------------------
__global__ __launch_bounds__(256) void transpose_cast(const float* __restrict__ W,
                                                      unsigned short* __restrict__ Wt,
                                                      int N, float scale) {
  __shared__ float tile[32][33];
  int bx = blockIdx.x * 32;  // n-range
  int by = blockIdx.y * 32;  // k-range
  int tx = threadIdx.x, ty = threadIdx.y;  // 32 x 8
#pragma unroll
  for (int i = 0; i < 4; ++i)
    tile[ty + i * 8][tx] = W[(size_t)(by + ty + i * 8) * N + bx + tx];
  __syncthreads();
#pragma unroll
  for (int i = 0; i < 4; ++i)
    Wt[(size_t)(bx + ty + i * 8) * N + by + tx] = f2bf(tile[tx][ty + i * 8] * scale);
}

// ---------------------------------------------------------------------------
// Per-head V transpose: Vp [B,S,D] bf16 -> Vt [B*H][DEPTH][S] bf16
// ---------------------------------------------------------------------------
__global__ __launch_bounds__(256) void transpose_v(const unsigned short* __restrict__ Vp,
                                                   unsigned short* __restrict__ Vt) {
  __shared__ unsigned short tile[64][72];  // tile[d][s_local]
  int tid = threadIdx.x;
  int sb = blockIdx.x;   // 0..31
  int bh = blockIdx.y;   // 0..63
  int b = bh >> 4, h = bh & 15;
  int s0 = sb * 64;
#pragma unroll
  for (int rep = 0; rep < 2; ++rep) {
    int idx = rep * 256 + tid;
    int r = idx >> 3, c8 = idx & 7;
    us8 v = *(const us8*)(Vp + (size_t)(b * S_LEN + s0 + r) * D_MODEL + h * DEPTH + c8 * 8);
#pragma unroll
    for (int e = 0; e < 8; ++e) tile[c8 * 8 + e][r] = v[e];
  }
  __syncthreads();
#pragma unroll
  for (int rep = 0; rep < 2; ++rep) {
    int idx = rep * 256 + tid;
    int d = idx >> 3, c8 = idx & 7;
    us8 v = *(const us8*)&tile[d][c8 * 8];
    *(us8*)(Vt + ((size_t)(bh * DEPTH + d)) * S_LEN + s0 + c8 * 8) = v;
  }
}

// ---------------------------------------------------------------------------
// GEMM:  C[M][N] = A[M][K] @ Bt[N][K]^T + bias*bscale
// m97-style single-buffer 2-barrier K-loop at 4 blocks/CU (34/32 KB LDS).
// B (and bf16 A) via global_load_lds: XOR-swizzled SOURCE + linear dest +
// matching XOR on read (conflict-free ds_read_b128). fp32 A: reg prefetch
// of tile k+1 issued before compute(k) (T14), HW bf16 cast, pad-72 LDS.
// Multi-slice fusion via blockIdx.y (QKV in one dispatch). Natural block
// map: same-A blocks are 64 apart in dispatch order -> same XCD (64%8==0).
// ---------------------------------------------------------------------------
struct GemmSlice {
  const void* A;
  const unsigned short* Bt;
  const float* bias;
  void* C;
  float bscale;
};
struct GemmArgs {
  GemmSlice s[3];
};

template <bool A_IS_F32, bool OUT_F32>
__global__ __launch_bounds__(256, 4) void gemm_bt(GemmArgs args, int M, int N, int K) {
  constexpr int ASTR = A_IS_F32 ? 72 : 64;
  __shared__ unsigned short a_lds[128 * ASTR];
  __shared__ unsigned short b_lds[128 * 64];

  int slice = blockIdx.y >> 3;
  int nj = blockIdx.y & 7;
  const GemmSlice& g = args.s[slice];
  const float* Af = (const float*)g.A;
  const unsigned short* Ah = (const unsigned short*)g.A;
  const unsigned short* Bt = g.Bt;

  int tid = threadIdx.x;
  int wave = tid >> 6, lane = tid & 63;
  int l15 = lane & 15, lg = lane >> 4;
  int wm = wave >> 1, wn = wave & 1;

  int row0 = blockIdx.x * 128;
  int col0 = nj * 128;

  f32x4 acc[4][4] = {};
  f32x4 av[8];  // in-flight A tile (fp32 path)

  int ar = tid >> 4, ac4 = tid & 15;  // fp32-A staging coords

  auto loadA = [&](int k0) {
#pragma unroll
    for (int rep = 0; rep < 8; ++rep)
      av[rep] = *(const f32x4*)(Af + (size_t)(row0 + rep * 16 + ar) * K + k0 + ac4 * 4);
  };
  auto writeA = [&]() {
#pragma unroll
    for (int rep = 0; rep < 8; ++rep) {
      us4 h = {f2bf_hw(av[rep][0]), f2bf_hw(av[rep][1]),
               f2bf_hw(av[rep][2]), f2bf_hw(av[rep][3])};
      *(us4*)&a_lds[(rep * 16 + ar) * 72 + ac4 * 4] = h;
    }
  };
  auto issueA = [&](int k0) {  // bf16-A via glds, swizzled source
#pragma unroll
    for (int rep = 0; rep < 4; ++rep) {
      int chunk = (wave * 4 + rep) * 64 + lane;
      int row = chunk >> 3;
      int c8 = (chunk & 7) ^ (row & 7);
      __builtin_amdgcn_global_load_lds(
          (const GLOBAL_AS void*)(Ah + (size_t)(row0 + row) * K + k0 + c8 * 8),
          (LDS_AS void*)(&a_lds[chunk * 8]), 16, 0, 0);
    }
  };
  auto issueB = [&](int k0) {
#pragma unroll
    for (int rep = 0; rep < 4; ++rep) {
      int chunk = (wave * 4 + rep) * 64 + lane;
      int row = chunk >> 3;
      int c8 = (chunk & 7) ^ (row & 7);
      __builtin_amdgcn_global_load_lds(
          (const GLOBAL_AS void*)(Bt + (size_t)(col0 + row) * K + k0 + c8 * 8),
          (LDS_AS void*)(&b_lds[chunk * 8]), 16, 0, 0);
    }
  };
  auto compute = [&]() {
#pragma unroll
    for (int kk = 0; kk < 2; ++kk) {
      bf16x8 af[4], bfr[4];
#pragma unroll
      for (int ii = 0; ii < 4; ++ii) {
        int row = wm * 64 + ii * 16 + l15;
        if constexpr (A_IS_F32)
          af[ii] = *(const bf16x8*)&a_lds[row * 72 + kk * 32 + lg * 8];
        else
          af[ii] = *(const bf16x8*)&a_lds[row * 64 + (((kk * 4 + lg) ^ (l15 & 7)) * 8)];
      }
#pragma unroll
      for (int jj = 0; jj < 4; ++jj) {
        int row = wn * 64 + jj * 16 + l15;
        bfr[jj] = *(const bf16x8*)&b_lds[row * 64 + (((kk * 4 + lg) ^ (l15 & 7)) * 8)];
      }
#pragma unroll
      for (int ii = 0; ii < 4; ++ii)
#pragma unroll
        for (int jj = 0; jj < 4; ++jj)
          acc[ii][jj] = __builtin_amdgcn_mfma_f32_16x16x32_bf16(af[ii], bfr[jj], acc[ii][jj], 0, 0, 0);
    }
  };

  int nk = K >> 6;
  if constexpr (A_IS_F32) loadA(0);

  for (int ki = 0; ki < nk; ++ki) {
    __syncthreads();  // readers of previous tile done
    issueB(ki * 64);
    if constexpr (A_IS_F32)
      writeA();
    else
      issueA(ki * 64);
    __syncthreads();  // drains vmcnt (glds) + lgkm (A writes): tile visible
    if constexpr (A_IS_F32) {
      if (ki + 1 < nk) loadA((ki + 1) * 64);  // prefetch under the MFMAs
    }
    compute();
  }

  // ---- epilogue ----
#pragma unroll
  for (int ii = 0; ii < 4; ++ii) {
#pragma unroll
    for (int jj = 0; jj < 4; ++jj) {
      int col = col0 + wn * 64 + jj * 16 + l15;
      float bv = g.bias[col] * g.bscale;
#pragma unroll
      for (int r = 0; r < 4; ++r) {
        int row = row0 + wm * 64 + ii * 16 + lg * 4 + r;
        float v = acc[ii][jj][r] + bv;
        if constexpr (OUT_F32)
          ((float*)g.C)[(size_t)row * N + col] = v;
        else
          ((unsigned short*)g.C)[(size_t)row * N + col] = f2bf(v);
      }
    }
  }
}

// ---------------------------------------------------------------------------
// Causal flash attention. Q pre-scaled by 0.125*log2(e); NO-MAX exp2
// softmax; l via ones-MFMA (compute body frozen since r4). This round:
// SINGLE-buffered K/V^T (39 KB LDS -> 4 blocks/CU = 100% wave cap), two
// barriers/step, T14 reg prefetch: tile k+1 global loads issued before
// compute(k), LDS write after the readers-done barrier.
// ---------------------------------------------------------------------------
__global__ __launch_bounds__(512, 8) void attn_kernel(const unsigned short* __restrict__ Qp,
                                                      const unsigned short* __restrict__ Kp,
                                                      const unsigned short* __restrict__ Vt,
                                                      unsigned short* __restrict__ Op) {
  __shared__ unsigned short k_lds[64][76];
  __shared__ unsigned short vt_lds[64][76];   // [d][k]
  __shared__ unsigned short p_lds[8][16][76];

  int tid = threadIdx.x;
  int w = tid >> 6, lane = tid & 63;
  int l15 = lane & 15, lg = lane >> 4;

  int bid = blockIdx.x;                    // 0..511
  int swz = (bid & 7) * 64 + (bid >> 3);   // bijective (512 % 8 == 0)
  int pairIdx = swz & 7;                   // 0..7
  int bh = swz >> 3;                       // 0..63 (8 bh per XCD)
  int b = bh >> 4, h = bh & 15;

  const unsigned short* Kbase = Kp + (size_t)b * S_LEN * D_MODEL + h * DEPTH;
  const unsigned short* Vbase = Vt + (size_t)bh * DEPTH * S_LEN;

  bool stageV = (tid >= 256);
  int st = tid & 255;
  int r = st >> 2, cb = (st & 3) * 16;
  const unsigned short* srow = stageV ? (Vbase + (size_t)r * S_LEN + cb)
                                      : (Kbase + (size_t)r * D_MODEL + cb);
  const size_t sstep = stageV ? 64 : (size_t)64 * D_MODEL;

  bf16x8 ones;
#pragma unroll
  for (int e = 0; e < 8; ++e) ones[e] = (short)0x3F80;

  for (int half = 0; half < 2; ++half) {
    int t = (half == 0) ? pairIdx : (15 - pairIdx);
    int q0 = t * 128;
    int nkv = 2 * t + 2;
    int q0w = q0 + w * 16;

    const unsigned short* qp =
        Qp + ((size_t)(b * S_LEN + q0 + w * 16 + l15)) * D_MODEL + h * DEPTH;
    bf16x8 qf0 = *(const bf16x8*)(qp + lg * 8);
    bf16x8 qf1 = *(const bf16x8*)(qp + 32 + lg * 8);

    f32x4 acc_l = (f32x4){0.f, 0.f, 0.f, 0.f};
    f32x4 acc_o[4];
#pragma unroll
    for (int dd = 0; dd < 4; ++dd) acc_o[dd] = (f32x4){0.f, 0.f, 0.f, 0.f};

    // prologue: load tile 0 into regs
    const unsigned short* sptr = srow;
    us8 s0 = *(const us8*)sptr;
    us8 s1 = *(const us8*)(sptr + 8);
    sptr += sstep;

    for (int kb = 0; kb < nkv; ++kb) {
      int k0 = kb * 64;
      __syncthreads();  // readers of tile kb-1 (or prior half) done
      if (stageV) {
        *(us8*)&vt_lds[r][cb] = s0;
        *(us8*)&vt_lds[r][cb + 8] = s1;
      } else {
        *(us8*)&k_lds[r][cb] = s0;
        *(us8*)&k_lds[r][cb + 8] = s1;
      }
      __syncthreads();  // tile kb visible
      bool more = (kb + 1) < nkv;
      if (more) {
        s0 = *(const us8*)sptr;      // issue next tile's loads early (T14);
        s1 = *(const us8*)(sptr + 8);  // latency hides under compute below
        sptr += sstep;
      }

      bool full_masked = (k0 > q0w + 15);
      if (!full_masked) {
        f32x4 s[4];
#pragma unroll
        for (int nf = 0; nf < 4; ++nf) s[nf] = (f32x4){0.f, 0.f, 0.f, 0.f};
        __builtin_amdgcn_s_setprio(1);
#pragma unroll
        for (int nf = 0; nf < 4; ++nf) {
          bf16x8 kf0 = *(const bf16x8*)&k_lds[nf * 16 + l15][lg * 8];
          bf16x8 kf1 = *(const bf16x8*)&k_lds[nf * 16 + l15][32 + lg * 8];
          s[nf] = __builtin_amdgcn_mfma_f32_16x16x32_bf16(qf0, kf0, s[nf], 0, 0, 0);
          s[nf] = __builtin_amdgcn_mfma_f32_16x16x32_bf16(qf1, kf1, s[nf], 0, 0, 0);
        }
        __builtin_amdgcn_s_setprio(0);

        bool diag = (k0 + 63 > q0w);
        if (diag) {
#pragma unroll
          for (int nf = 0; nf < 4; ++nf)
#pragma unroll
            for (int rr = 0; rr < 4; ++rr) {
              int qrow = q0w + lg * 4 + rr;
              int kcol = k0 + nf * 16 + l15;
              float x = (kcol > qrow) ? -1e10f : s[nf][rr];
              float p = __builtin_amdgcn_exp2f(x);
              p_lds[w][lg * 4 + rr][nf * 16 + l15] =
                  (unsigned short)(__builtin_bit_cast(unsigned int, p) >> 16);
            }
        } else {
#pragma unroll
          for (int nf = 0; nf < 4; ++nf)
#pragma unroll
            for (int rr = 0; rr < 4; ++rr) {
              float p = __builtin_amdgcn_exp2f(s[nf][rr]);
              p_lds[w][lg * 4 + rr][nf * 16 + l15] =
                  (unsigned short)(__builtin_bit_cast(unsigned int, p) >> 16);
            }
        }

        __builtin_amdgcn_s_setprio(1);
#pragma unroll
        for (int kk = 0; kk < 2; ++kk) {
          bf16x8 pf = *(const bf16x8*)&p_lds[w][l15][kk * 32 + lg * 8];
          acc_l = __builtin_amdgcn_mfma_f32_16x16x32_bf16(pf, ones, acc_l, 0, 0, 0);
#pragma unroll
          for (int dd = 0; dd < 4; ++dd) {
            bf16x8 vf = *(const bf16x8*)&vt_lds[dd * 16 + l15][kk * 32 + lg * 8];
            acc_o[dd] = __builtin_amdgcn_mfma_f32_16x16x32_bf16(pf, vf, acc_o[dd], 0, 0, 0);
          }
        }
        __builtin_amdgcn_s_setprio(0);
      }
    }

#pragma unroll
    for (int rr = 0; rr < 4; ++rr) {
      float inv = 1.0f / acc_l[rr];
      int qrow = q0 + w * 16 + lg * 4 + rr;
      unsigned short* op = Op + ((size_t)(b * S_LEN + qrow)) * D_MODEL + h * DEPTH;
#pragma unroll
      for (int dd = 0; dd < 4; ++dd)
        op[dd * 16 + l15] = f2bf(acc_o[dd][rr] * inv);
    }
  }
}

// ---------------------------------------------------------------------------
extern "C" void kernel_launch(void* const* d_in, const int* in_sizes, int n_in,
                              void* d_out, int out_size, void* d_ws, size_t ws_size,
                              hipStream_t stream) {
  const float* q  = (const float*)d_in[0];
  const float* v  = (const float*)d_in[1];
  const float* k  = (const float*)d_in[2];
  const float* Wq = (const float*)d_in[3];
  const float* bq = (const float*)d_in[4];
  const float* Wk = (const float*)d_in[5];
  const float* bk = (const float*)d_in[6];
  const float* Wv = (const float*)d_in[7];
  const float* bv = (const float*)d_in[8];
  const float* Wo = (const float*)d_in[9];
  const float* bo = (const float*)d_in[10];

  char* ws = (char*)d_ws;
  const size_t WSZ = (size_t)D_MODEL * D_MODEL * 2;        // 2 MB per weight
  const size_t XSZ = (size_t)BATCH * S_LEN * D_MODEL * 2;  // 16 MB per activation
  unsigned short* Wqt = (unsigned short*)(ws);
  unsigned short* Wkt = (unsigned short*)(ws + WSZ);
  unsigned short* Wvt = (unsigned short*)(ws + 2 * WSZ);
  unsigned short* Wot = (unsigned short*)(ws + 3 * WSZ);
  unsigned short* Qp  = (unsigned short*)(ws + 4 * WSZ);
  unsigned short* Kp  = (unsigned short*)(ws + 4 * WSZ + XSZ);
  unsigned short* Vp  = (unsigned short*)(ws + 4 * WSZ + 2 * XSZ);
  unsigned short* Vtp = (unsigned short*)(ws + 4 * WSZ + 3 * XSZ);
  unsigned short* AO  = Vp;  // alias: Vp fully consumed by transpose_v before attn writes AO

  const float SCL = 0.125f * 1.4426950408889634f;
  const int M = BATCH * S_LEN;

  dim3 tb(32, 8);
  dim3 tg(D_MODEL / 32, D_MODEL / 32);
  hipLaunchKernelGGL(transpose_cast, tg, tb, 0, stream, Wq, Wqt, D_MODEL, SCL);
  hipLaunchKernelGGL(transpose_cast, tg, tb, 0, stream, Wk, Wkt, D_MODEL, 1.0f);
  hipLaunchKernelGGL(transpose_cast, tg, tb, 0, stream, Wv, Wvt, D_MODEL, 1.0f);
  hipLaunchKernelGGL(transpose_cast, tg, tb, 0, stream, Wo, Wot, D_MODEL, 1.0f);

  GemmArgs qkv{};
  qkv.s[0] = GemmSlice{(const void*)q, Wqt, bq, (void*)Qp, SCL};
  qkv.s[1] = GemmSlice{(const void*)k, Wkt, bk, (void*)Kp, 1.0f};
  qkv.s[2] = GemmSlice{(const void*)v, Wvt, bv, (void*)Vp, 1.0f};
  hipLaunchKernelGGL((gemm_bt<true, false>), dim3(M / 128, 24), dim3(256), 0, stream,
                     qkv, M, D_MODEL, D_MODEL);

  hipLaunchKernelGGL(transpose_v, dim3(S_LEN / 64, BATCH * N_HEADS), dim3(256), 0, stream,
                     Vp, Vtp);

  hipLaunchKernelGGL(attn_kernel, dim3(512), dim3(512), 0, stream, Qp, Kp, Vtp, AO);

  GemmArgs ao{};
  ao.s[0] = GemmSlice{(const void*)AO, Wot, bo, d_out, 1.0f};
  hipLaunchKernelGGL((gemm_bt<false, true>), dim3(M / 128, 8), dim3(256), 0, stream,
                     ao, M, D_MODEL, D_MODEL);
}

// Round 8
// 222.795 us; speedup vs baseline: 2.0670x; 2.0670x over previous
//
#include <hip/hip_runtime.h>
#include <hip/hip_bf16.h>
#include <cstdint>
#include <cstddef>

#define S_LEN 2048
#define D_MODEL 1024
#define N_HEADS 16
#define DEPTH 64
#define BATCH 4

#define GLOBAL_AS __attribute__((address_space(1)))
#define LDS_AS __attribute__((address_space(3)))

typedef __attribute__((ext_vector_type(4))) float f32x4;
typedef __attribute__((ext_vector_type(8))) short bf16x8;
typedef __attribute__((ext_vector_type(4))) unsigned short us4;
typedef __attribute__((ext_vector_type(8))) unsigned short us8;

__device__ __forceinline__ unsigned short f2bf(float f) {
  unsigned int u = __builtin_bit_cast(unsigned int, f);
  u += 0x7FFFu + ((u >> 16) & 1u);   // round-to-nearest-even
  return (unsigned short)(u >> 16);
}

// HW cast (compiler emits v_cvt_pk_bf16_f32 pairs)
__device__ __forceinline__ unsigned short f2bf_hw(float f) {
  return __builtin_bit_cast(unsigned short, __float2bfloat16(f));
}

// ---------------------------------------------------------------------------
// Weight transpose + scale + fp32 -> bf16 cast:  Wt[n][k] = W[k][n] * scale
// ---------------------------------------------------------------------------
__global__ __launch_bounds__(256) void transpose_cast(const float* __restrict__ W,
                                                      unsigned short* __restrict__ Wt,
                                                      int N, float scale) {
  __shared__ float tile[32][33];
  int bx = blockIdx.x * 32;  // n-range
  int by = blockIdx.y * 32;  // k-range
  int tx = threadIdx.x, ty = threadIdx.y;  // 32 x 8
#pragma unroll
  for (int i = 0; i < 4; ++i)
    tile[ty + i * 8][tx] = W[(size_t)(by + ty + i * 8) * N + bx + tx];
  __syncthreads();
#pragma unroll
  for (int i = 0; i < 4; ++i)
    Wt[(size_t)(bx + ty + i * 8) * N + by + tx] = f2bf(tile[tx][ty + i * 8] * scale);
}

// ---------------------------------------------------------------------------
// Per-head V transpose: Vp [B,S,D] bf16 -> Vt [B*H][DEPTH][S] bf16
// ---------------------------------------------------------------------------
__global__ __launch_bounds__(256) void transpose_v(const unsigned short* __restrict__ Vp,
                                                   unsigned short* __restrict__ Vt) {
  __shared__ unsigned short tile[64][72];  // tile[d][s_local]
  int tid = threadIdx.x;
  int sb = blockIdx.x;   // 0..31
  int bh = blockIdx.y;   // 0..63
  int b = bh >> 4, h = bh & 15;
  int s0 = sb * 64;
#pragma unroll
  for (int rep = 0; rep < 2; ++rep) {
    int idx = rep * 256 + tid;
    int r = idx >> 3, c8 = idx & 7;
    us8 v = *(const us8*)(Vp + (size_t)(b * S_LEN + s0 + r) * D_MODEL + h * DEPTH + c8 * 8);
#pragma unroll
    for (int e = 0; e < 8; ++e) tile[c8 * 8 + e][r] = v[e];
  }
  __syncthreads();
#pragma unroll
  for (int rep = 0; rep < 2; ++rep) {
    int idx = rep * 256 + tid;
    int d = idx >> 3, c8 = idx & 7;
    us8 v = *(const us8*)&tile[d][c8 * 8];
    *(us8*)(Vt + ((size_t)(bh * DEPTH + d)) * S_LEN + s0 + c8 * 8) = v;
  }
}

// ---------------------------------------------------------------------------
// GEMM:  C[M][N] = A[M][K] @ Bt[N][K]^T + bias*bscale
// m97-style single-buffer 2-barrier K-loop. NO min-waves bound: r6's
// __launch_bounds__(256,4) capped VGPR at 64 -> accumulator spilled to
// scratch (WRITE_SIZE 550 MB, 375 us). Uncapped VGPR ~160 = m97's proven
// operating point (~3 blocks/CU). B (and bf16 A) via global_load_lds:
// XOR-swizzled SOURCE + linear dest + matching XOR on read. fp32 A: reg
// prefetch of tile k+1 issued before compute(k) (T14), HW bf16 cast,
// pad-72 LDS. Multi-slice fusion via blockIdx.y (QKV in one dispatch).
// ---------------------------------------------------------------------------
struct GemmSlice {
  const void* A;
  const unsigned short* Bt;
  const float* bias;
  void* C;
  float bscale;
};
struct GemmArgs {
  GemmSlice s[3];
};

template <bool A_IS_F32, bool OUT_F32>
__global__ __launch_bounds__(256) void gemm_bt(GemmArgs args, int M, int N, int K) {
  constexpr int ASTR = A_IS_F32 ? 72 : 64;
  __shared__ unsigned short a_lds[128 * ASTR];
  __shared__ unsigned short b_lds[128 * 64];

  int slice = blockIdx.y >> 3;
  int nj = blockIdx.y & 7;
  const GemmSlice& g = args.s[slice];
  const float* Af = (const float*)g.A;
  const unsigned short* Ah = (const unsigned short*)g.A;
  const unsigned short* Bt = g.Bt;

  int tid = threadIdx.x;
  int wave = tid >> 6, lane = tid & 63;
  int l15 = lane & 15, lg = lane >> 4;
  int wm = wave >> 1, wn = wave & 1;

  int row0 = blockIdx.x * 128;
  int col0 = nj * 128;

  f32x4 acc[4][4] = {};
  f32x4 av[8];  // in-flight A tile (fp32 path)

  int ar = tid >> 4, ac4 = tid & 15;  // fp32-A staging coords

  auto loadA = [&](int k0) {
#pragma unroll
    for (int rep = 0; rep < 8; ++rep)
      av[rep] = *(const f32x4*)(Af + (size_t)(row0 + rep * 16 + ar) * K + k0 + ac4 * 4);
  };
  auto writeA = [&]() {
#pragma unroll
    for (int rep = 0; rep < 8; ++rep) {
      us4 h = {f2bf_hw(av[rep][0]), f2bf_hw(av[rep][1]),
               f2bf_hw(av[rep][2]), f2bf_hw(av[rep][3])};
      *(us4*)&a_lds[(rep * 16 + ar) * 72 + ac4 * 4] = h;
    }
  };
  auto issueA = [&](int k0) {  // bf16-A via glds, swizzled source
#pragma unroll
    for (int rep = 0; rep < 4; ++rep) {
      int chunk = (wave * 4 + rep) * 64 + lane;
      int row = chunk >> 3;
      int c8 = (chunk & 7) ^ (row & 7);
      __builtin_amdgcn_global_load_lds(
          (const GLOBAL_AS void*)(Ah + (size_t)(row0 + row) * K + k0 + c8 * 8),
          (LDS_AS void*)(&a_lds[chunk * 8]), 16, 0, 0);
    }
  };
  auto issueB = [&](int k0) {
#pragma unroll
    for (int rep = 0; rep < 4; ++rep) {
      int chunk = (wave * 4 + rep) * 64 + lane;
      int row = chunk >> 3;
      int c8 = (chunk & 7) ^ (row & 7);
      __builtin_amdgcn_global_load_lds(
          (const GLOBAL_AS void*)(Bt + (size_t)(col0 + row) * K + k0 + c8 * 8),
          (LDS_AS void*)(&b_lds[chunk * 8]), 16, 0, 0);
    }
  };
  auto compute = [&]() {
#pragma unroll
    for (int kk = 0; kk < 2; ++kk) {
      bf16x8 af[4], bfr[4];
#pragma unroll
      for (int ii = 0; ii < 4; ++ii) {
        int row = wm * 64 + ii * 16 + l15;
        if constexpr (A_IS_F32)
          af[ii] = *(const bf16x8*)&a_lds[row * 72 + kk * 32 + lg * 8];
        else
          af[ii] = *(const bf16x8*)&a_lds[row * 64 + (((kk * 4 + lg) ^ (l15 & 7)) * 8)];
      }
#pragma unroll
      for (int jj = 0; jj < 4; ++jj) {
        int row = wn * 64 + jj * 16 + l15;
        bfr[jj] = *(const bf16x8*)&b_lds[row * 64 + (((kk * 4 + lg) ^ (l15 & 7)) * 8)];
      }
#pragma unroll
      for (int ii = 0; ii < 4; ++ii)
#pragma unroll
        for (int jj = 0; jj < 4; ++jj)
          acc[ii][jj] = __builtin_amdgcn_mfma_f32_16x16x32_bf16(af[ii], bfr[jj], acc[ii][jj], 0, 0, 0);
    }
  };

  int nk = K >> 6;
  if constexpr (A_IS_F32) loadA(0);

  for (int ki = 0; ki < nk; ++ki) {
    __syncthreads();  // readers of previous tile done
    issueB(ki * 64);
    if constexpr (A_IS_F32)
      writeA();
    else
      issueA(ki * 64);
    __syncthreads();  // drains vmcnt (glds) + lgkm (A writes): tile visible
    if constexpr (A_IS_F32) {
      if (ki + 1 < nk) loadA((ki + 1) * 64);  // prefetch under the MFMAs
    }
    compute();
  }

  // ---- epilogue ----
#pragma unroll
  for (int ii = 0; ii < 4; ++ii) {
#pragma unroll
    for (int jj = 0; jj < 4; ++jj) {
      int col = col0 + wn * 64 + jj * 16 + l15;
      float bv = g.bias[col] * g.bscale;
#pragma unroll
      for (int r = 0; r < 4; ++r) {
        int row = row0 + wm * 64 + ii * 16 + lg * 4 + r;
        float v = acc[ii][jj][r] + bv;
        if constexpr (OUT_F32)
          ((float*)g.C)[(size_t)row * N + col] = v;
        else
          ((unsigned short*)g.C)[(size_t)row * N + col] = f2bf(v);
      }
    }
  }
}

// ---------------------------------------------------------------------------
// Causal flash attention. Q pre-scaled by 0.125*log2(e); NO-MAX exp2
// softmax; l via ones-MFMA. Single-buffered K/V^T (39 KB LDS -> 4 blocks/CU),
// two barriers/step, T14 reg prefetch. (512,8) cap is safe: measured 52 VGPR.
// ---------------------------------------------------------------------------
__global__ __launch_bounds__(512, 8) void attn_kernel(const unsigned short* __restrict__ Qp,
                                                      const unsigned short* __restrict__ Kp,
                                                      const unsigned short* __restrict__ Vt,
                                                      unsigned short* __restrict__ Op) {
  __shared__ unsigned short k_lds[64][76];
  __shared__ unsigned short vt_lds[64][76];   // [d][k]
  __shared__ unsigned short p_lds[8][16][76];

  int tid = threadIdx.x;
  int w = tid >> 6, lane = tid & 63;
  int l15 = lane & 15, lg = lane >> 4;

  int bid = blockIdx.x;                    // 0..511
  int swz = (bid & 7) * 64 + (bid >> 3);   // bijective (512 % 8 == 0)
  int pairIdx = swz & 7;                   // 0..7
  int bh = swz >> 3;                       // 0..63 (8 bh per XCD)
  int b = bh >> 4, h = bh & 15;

  const unsigned short* Kbase = Kp + (size_t)b * S_LEN * D_MODEL + h * DEPTH;
  const unsigned short* Vbase = Vt + (size_t)bh * DEPTH * S_LEN;

  bool stageV = (tid >= 256);
  int st = tid & 255;
  int r = st >> 2, cb = (st & 3) * 16;
  const unsigned short* srow = stageV ? (Vbase + (size_t)r * S_LEN + cb)
                                      : (Kbase + (size_t)r * D_MODEL + cb);
  const size_t sstep = stageV ? 64 : (size_t)64 * D_MODEL;

  bf16x8 ones;
#pragma unroll
  for (int e = 0; e < 8; ++e) ones[e] = (short)0x3F80;

  for (int half = 0; half < 2; ++half) {
    int t = (half == 0) ? pairIdx : (15 - pairIdx);
    int q0 = t * 128;
    int nkv = 2 * t + 2;
    int q0w = q0 + w * 16;

    const unsigned short* qp =
        Qp + ((size_t)(b * S_LEN + q0 + w * 16 + l15)) * D_MODEL + h * DEPTH;
    bf16x8 qf0 = *(const bf16x8*)(qp + lg * 8);
    bf16x8 qf1 = *(const bf16x8*)(qp + 32 + lg * 8);

    f32x4 acc_l = (f32x4){0.f, 0.f, 0.f, 0.f};
    f32x4 acc_o[4];
#pragma unroll
    for (int dd = 0; dd < 4; ++dd) acc_o[dd] = (f32x4){0.f, 0.f, 0.f, 0.f};

    // prologue: load tile 0 into regs
    const unsigned short* sptr = srow;
    us8 s0 = *(const us8*)sptr;
    us8 s1 = *(const us8*)(sptr + 8);
    sptr += sstep;

    for (int kb = 0; kb < nkv; ++kb) {
      int k0 = kb * 64;
      __syncthreads();  // readers of tile kb-1 (or prior half) done
      if (stageV) {
        *(us8*)&vt_lds[r][cb] = s0;
        *(us8*)&vt_lds[r][cb + 8] = s1;
      } else {
        *(us8*)&k_lds[r][cb] = s0;
        *(us8*)&k_lds[r][cb + 8] = s1;
      }
      __syncthreads();  // tile kb visible
      bool more = (kb + 1) < nkv;
      if (more) {
        s0 = *(const us8*)sptr;        // issue next tile's loads early (T14);
        s1 = *(const us8*)(sptr + 8);  // latency hides under compute below
        sptr += sstep;
      }

      bool full_masked = (k0 > q0w + 15);
      if (!full_masked) {
        f32x4 s[4];
#pragma unroll
        for (int nf = 0; nf < 4; ++nf) s[nf] = (f32x4){0.f, 0.f, 0.f, 0.f};
        __builtin_amdgcn_s_setprio(1);
#pragma unroll
        for (int nf = 0; nf < 4; ++nf) {
          bf16x8 kf0 = *(const bf16x8*)&k_lds[nf * 16 + l15][lg * 8];
          bf16x8 kf1 = *(const bf16x8*)&k_lds[nf * 16 + l15][32 + lg * 8];
          s[nf] = __builtin_amdgcn_mfma_f32_16x16x32_bf16(qf0, kf0, s[nf], 0, 0, 0);
          s[nf] = __builtin_amdgcn_mfma_f32_16x16x32_bf16(qf1, kf1, s[nf], 0, 0, 0);
        }
        __builtin_amdgcn_s_setprio(0);

        bool diag = (k0 + 63 > q0w);
        if (diag) {
#pragma unroll
          for (int nf = 0; nf < 4; ++nf)
#pragma unroll
            for (int rr = 0; rr < 4; ++rr) {
              int qrow = q0w + lg * 4 + rr;
              int kcol = k0 + nf * 16 + l15;
              float x = (kcol > qrow) ? -1e10f : s[nf][rr];
              float p = __builtin_amdgcn_exp2f(x);
              p_lds[w][lg * 4 + rr][nf * 16 + l15] =
                  (unsigned short)(__builtin_bit_cast(unsigned int, p) >> 16);
            }
        } else {
#pragma unroll
          for (int nf = 0; nf < 4; ++nf)
#pragma unroll
            for (int rr = 0; rr < 4; ++rr) {
              float p = __builtin_amdgcn_exp2f(s[nf][rr]);
              p_lds[w][lg * 4 + rr][nf * 16 + l15] =
                  (unsigned short)(__builtin_bit_cast(unsigned int, p) >> 16);
            }
        }

        __builtin_amdgcn_s_setprio(1);
#pragma unroll
        for (int kk = 0; kk < 2; ++kk) {
          bf16x8 pf = *(const bf16x8*)&p_lds[w][l15][kk * 32 + lg * 8];
          acc_l = __builtin_amdgcn_mfma_f32_16x16x32_bf16(pf, ones, acc_l, 0, 0, 0);
#pragma unroll
          for (int dd = 0; dd < 4; ++dd) {
            bf16x8 vf = *(const bf16x8*)&vt_lds[dd * 16 + l15][kk * 32 + lg * 8];
            acc_o[dd] = __builtin_amdgcn_mfma_f32_16x16x32_bf16(pf, vf, acc_o[dd], 0, 0, 0);
          }
        }
        __builtin_amdgcn_s_setprio(0);
      }
    }

#pragma unroll
    for (int rr = 0; rr < 4; ++rr) {
      float inv = 1.0f / acc_l[rr];
      int qrow = q0 + w * 16 + lg * 4 + rr;
      unsigned short* op = Op + ((size_t)(b * S_LEN + qrow)) * D_MODEL + h * DEPTH;
#pragma unroll
      for (int dd = 0; dd < 4; ++dd)
        op[dd * 16 + l15] = f2bf(acc_o[dd][rr] * inv);
    }
  }
}

// ---------------------------------------------------------------------------
extern "C" void kernel_launch(void* const* d_in, const int* in_sizes, int n_in,
                              void* d_out, int out_size, void* d_ws, size_t ws_size,
                              hipStream_t stream) {
  const float* q  = (const float*)d_in[0];
  const float* v  = (const float*)d_in[1];
  const float* k  = (const float*)d_in[2];
  const float* Wq = (const float*)d_in[3];
  const float* bq = (const float*)d_in[4];
  const float* Wk = (const float*)d_in[5];
  const float* bk = (const float*)d_in[6];
  const float* Wv = (const float*)d_in[7];
  const float* bv = (const float*)d_in[8];
  const float* Wo = (const float*)d_in[9];
  const float* bo = (const float*)d_in[10];

  char* ws = (char*)d_ws;
  const size_t WSZ = (size_t)D_MODEL * D_MODEL * 2;        // 2 MB per weight
  const size_t XSZ = (size_t)BATCH * S_LEN * D_MODEL * 2;  // 16 MB per activation
  unsigned short* Wqt = (unsigned short*)(ws);
  unsigned short* Wkt = (unsigned short*)(ws + WSZ);
  unsigned short* Wvt = (unsigned short*)(ws + 2 * WSZ);
  unsigned short* Wot = (unsigned short*)(ws + 3 * WSZ);
  unsigned short* Qp  = (unsigned short*)(ws + 4 * WSZ);
  unsigned short* Kp  = (unsigned short*)(ws + 4 * WSZ + XSZ);
  unsigned short* Vp  = (unsigned short*)(ws + 4 * WSZ + 2 * XSZ);
  unsigned short* Vtp = (unsigned short*)(ws + 4 * WSZ + 3 * XSZ);
  unsigned short* AO  = Vp;  // alias: Vp fully consumed by transpose_v before attn writes AO

  const float SCL = 0.125f * 1.4426950408889634f;
  const int M = BATCH * S_LEN;

  dim3 tb(32, 8);
  dim3 tg(D_MODEL / 32, D_MODEL / 32);
  hipLaunchKernelGGL(transpose_cast, tg, tb, 0, stream, Wq, Wqt, D_MODEL, SCL);
  hipLaunchKernelGGL(transpose_cast, tg, tb, 0, stream, Wk, Wkt, D_MODEL, 1.0f);
  hipLaunchKernelGGL(transpose_cast, tg, tb, 0, stream, Wv, Wvt, D_MODEL, 1.0f);
  hipLaunchKernelGGL(transpose_cast, tg, tb, 0, stream, Wo, Wot, D_MODEL, 1.0f);

  GemmArgs qkv{};
  qkv.s[0] = GemmSlice{(const void*)q, Wqt, bq, (void*)Qp, SCL};
  qkv.s[1] = GemmSlice{(const void*)k, Wkt, bk, (void*)Kp, 1.0f};
  qkv.s[2] = GemmSlice{(const void*)v, Wvt, bv, (void*)Vp, 1.0f};
  hipLaunchKernelGGL((gemm_bt<true, false>), dim3(M / 128, 24), dim3(256), 0, stream,
                     qkv, M, D_MODEL, D_MODEL);

  hipLaunchKernelGGL(transpose_v, dim3(S_LEN / 64, BATCH * N_HEADS), dim3(256), 0, stream,
                     Vp, Vtp);

  hipLaunchKernelGGL(attn_kernel, dim3(512), dim3(512), 0, stream, Qp, Kp, Vtp, AO);

  GemmArgs ao{};
  ao.s[0] = GemmSlice{(const void*)AO, Wot, bo, d_out, 1.0f};
  hipLaunchKernelGGL((gemm_bt<false, true>), dim3(M / 128, 8), dim3(256), 0, stream,
                     ao, M, D_MODEL, D_MODEL);
}

// Round 9
// 211.333 us; speedup vs baseline: 2.1792x; 1.0542x over previous
//
#include <hip/hip_runtime.h>
#include <hip/hip_bf16.h>
#include <cstdint>
#include <cstddef>

#define S_LEN 2048
#define D_MODEL 1024
#define N_HEADS 16
#define DEPTH 64
#define BATCH 4

#define GLOBAL_AS __attribute__((address_space(1)))
#define LDS_AS __attribute__((address_space(3)))

typedef __attribute__((ext_vector_type(4))) float f32x4;
typedef __attribute__((ext_vector_type(8))) short bf16x8;
typedef __attribute__((ext_vector_type(4))) unsigned short us4;
typedef __attribute__((ext_vector_type(8))) unsigned short us8;

__device__ __forceinline__ unsigned short f2bf(float f) {
  unsigned int u = __builtin_bit_cast(unsigned int, f);
  u += 0x7FFFu + ((u >> 16) & 1u);   // round-to-nearest-even
  return (unsigned short)(u >> 16);
}

// HW cast (compiler emits v_cvt_pk_bf16_f32 pairs)
__device__ __forceinline__ unsigned short f2bf_hw(float f) {
  return __builtin_bit_cast(unsigned short, __float2bfloat16(f));
}

// ---------------------------------------------------------------------------
// Fused weight transpose + scale + fp32 -> bf16 cast for all 4 weights:
// Wt[n][k] = W[k][n] * scale.  grid.z selects the weight.
// ---------------------------------------------------------------------------
struct TCArgs {
  const float* W[4];
  unsigned short* Wt[4];
  float scale[4];
};

__global__ __launch_bounds__(256) void transpose_cast4(TCArgs a, int N) {
  __shared__ float tile[32][33];
  int z = blockIdx.z;
  const float* W = a.W[z];
  unsigned short* Wt = a.Wt[z];
  float scale = a.scale[z];
  int bx = blockIdx.x * 32;  // n-range
  int by = blockIdx.y * 32;  // k-range
  int tx = threadIdx.x, ty = threadIdx.y;  // 32 x 8
#pragma unroll
  for (int i = 0; i < 4; ++i)
    tile[ty + i * 8][tx] = W[(size_t)(by + ty + i * 8) * N + bx + tx];
  __syncthreads();
#pragma unroll
  for (int i = 0; i < 4; ++i)
    Wt[(size_t)(bx + ty + i * 8) * N + by + tx] = f2bf(tile[tx][ty + i * 8] * scale);
}

// ---------------------------------------------------------------------------
// Per-head V transpose: Vp [B,S,D] bf16 -> Vt [B*H][DEPTH][S] bf16
// ---------------------------------------------------------------------------
__global__ __launch_bounds__(256) void transpose_v(const unsigned short* __restrict__ Vp,
                                                   unsigned short* __restrict__ Vt) {
  __shared__ unsigned short tile[64][72];  // tile[d][s_local]
  int tid = threadIdx.x;
  int sb = blockIdx.x;   // 0..31
  int bh = blockIdx.y;   // 0..63
  int b = bh >> 4, h = bh & 15;
  int s0 = sb * 64;
#pragma unroll
  for (int rep = 0; rep < 2; ++rep) {
    int idx = rep * 256 + tid;
    int r = idx >> 3, c8 = idx & 7;
    us8 v = *(const us8*)(Vp + (size_t)(b * S_LEN + s0 + r) * D_MODEL + h * DEPTH + c8 * 8);
#pragma unroll
    for (int e = 0; e < 8; ++e) tile[c8 * 8 + e][r] = v[e];
  }
  __syncthreads();
#pragma unroll
  for (int rep = 0; rep < 2; ++rep) {
    int idx = rep * 256 + tid;
    int d = idx >> 3, c8 = idx & 7;
    us8 v = *(const us8*)&tile[d][c8 * 8];
    *(us8*)(Vt + ((size_t)(bh * DEPTH + d)) * S_LEN + s0 + c8 * 8) = v;
  }
}

// ---------------------------------------------------------------------------
// GEMM:  C[M][N] = A[M][K] @ Bt[N][K]^T + bias*bscale
// r4's proven reg-staged 2-barrier K-loop (QKV ~90us) + ONE change: T14
// register prefetch of tile k+1 for BOTH operands, issued right after the
// visibility barrier so global latency hides under the 32 MFMAs. Between
// the barriers only LDS writes remain. bf16-A path (AO): A via glds
// (measured parity with reg-staging at K=1024), B reg-prefetched.
// No min-waves bound (r6: (256,4) capped VGPR at 64 -> spill catastrophe).
// ---------------------------------------------------------------------------
struct GemmSlice {
  const void* A;
  const unsigned short* Bt;
  const float* bias;
  void* C;
  float bscale;
};
struct GemmArgs {
  GemmSlice s[3];
};

template <bool A_IS_F32, bool OUT_F32>
__global__ __launch_bounds__(256) void gemm_bt(GemmArgs args, int M, int N, int K) {
  constexpr int ASTR = A_IS_F32 ? 72 : 64;
  __shared__ unsigned short a_lds[128 * ASTR];
  __shared__ unsigned short b_lds[128 * 72];

  int slice = blockIdx.y >> 3;
  int nj = blockIdx.y & 7;
  const GemmSlice& g = args.s[slice];
  const float* Af = (const float*)g.A;
  const unsigned short* Ah = (const unsigned short*)g.A;
  const unsigned short* Bt = g.Bt;

  int tid = threadIdx.x;
  int wave = tid >> 6, lane = tid & 63;
  int l15 = lane & 15, lg = lane >> 4;
  int wm = wave >> 1, wn = wave & 1;

  int row0 = blockIdx.x * 128;
  int col0 = nj * 128;

  f32x4 acc[4][4] = {};
  f32x4 av[8];  // in-flight A tile (fp32 path)
  us8 bv[4];    // in-flight B tile

  int ar = tid >> 4, ac4 = tid & 15;  // fp32-A staging coords
  int br = tid >> 3, bc8 = tid & 7;   // B staging coords

  auto loadA = [&](int k0) {
#pragma unroll
    for (int rep = 0; rep < 8; ++rep)
      av[rep] = *(const f32x4*)(Af + (size_t)(row0 + rep * 16 + ar) * K + k0 + ac4 * 4);
  };
  auto writeA = [&]() {
#pragma unroll
    for (int rep = 0; rep < 8; ++rep) {
      us4 h = {f2bf_hw(av[rep][0]), f2bf_hw(av[rep][1]),
               f2bf_hw(av[rep][2]), f2bf_hw(av[rep][3])};
      *(us4*)&a_lds[(rep * 16 + ar) * 72 + ac4 * 4] = h;
    }
  };
  auto loadB = [&](int k0) {
#pragma unroll
    for (int rep = 0; rep < 4; ++rep)
      bv[rep] = *(const us8*)(Bt + (size_t)(col0 + rep * 32 + br) * K + k0 + bc8 * 8);
  };
  auto writeB = [&]() {
#pragma unroll
    for (int rep = 0; rep < 4; ++rep)
      *(us8*)&b_lds[(rep * 32 + br) * 72 + bc8 * 8] = bv[rep];
  };
  auto issueA = [&](int k0) {  // bf16-A via glds, swizzled source (r7 form)
#pragma unroll
    for (int rep = 0; rep < 4; ++rep) {
      int chunk = (wave * 4 + rep) * 64 + lane;
      int row = chunk >> 3;
      int c8 = (chunk & 7) ^ (row & 7);
      __builtin_amdgcn_global_load_lds(
          (const GLOBAL_AS void*)(Ah + (size_t)(row0 + row) * K + k0 + c8 * 8),
          (LDS_AS void*)(&a_lds[chunk * 8]), 16, 0, 0);
    }
  };
  auto compute = [&]() {
#pragma unroll
    for (int kk = 0; kk < 2; ++kk) {
      bf16x8 af[4], bfr[4];
#pragma unroll
      for (int ii = 0; ii < 4; ++ii) {
        int row = wm * 64 + ii * 16 + l15;
        if constexpr (A_IS_F32)
          af[ii] = *(const bf16x8*)&a_lds[row * 72 + kk * 32 + lg * 8];
        else
          af[ii] = *(const bf16x8*)&a_lds[row * 64 + (((kk * 4 + lg) ^ (l15 & 7)) * 8)];
      }
#pragma unroll
      for (int jj = 0; jj < 4; ++jj) {
        int row = wn * 64 + jj * 16 + l15;
        bfr[jj] = *(const bf16x8*)&b_lds[row * 72 + kk * 32 + lg * 8];
      }
#pragma unroll
      for (int ii = 0; ii < 4; ++ii)
#pragma unroll
        for (int jj = 0; jj < 4; ++jj)
          acc[ii][jj] = __builtin_amdgcn_mfma_f32_16x16x32_bf16(af[ii], bfr[jj], acc[ii][jj], 0, 0, 0);
    }
  };

  int nk = K >> 6;
  loadB(0);
  if constexpr (A_IS_F32) loadA(0);

  for (int ki = 0; ki < nk; ++ki) {
    __syncthreads();  // readers of previous tile done
    writeB();
    if constexpr (A_IS_F32)
      writeA();
    else
      issueA(ki * 64);
    __syncthreads();  // tile visible (drains lgkm + vmcnt)
    if (ki + 1 < nk) {
      loadB((ki + 1) * 64);                    // prefetch next tile's regs —
      if constexpr (A_IS_F32) loadA((ki + 1) * 64);  // latency hides under MFMAs
    }
    compute();
  }

  // ---- epilogue ----
#pragma unroll
  for (int ii = 0; ii < 4; ++ii) {
#pragma unroll
    for (int jj = 0; jj < 4; ++jj) {
      int col = col0 + wn * 64 + jj * 16 + l15;
      float bv2 = g.bias[col] * g.bscale;
#pragma unroll
      for (int r = 0; r < 4; ++r) {
        int row = row0 + wm * 64 + ii * 16 + lg * 4 + r;
        float v = acc[ii][jj][r] + bv2;
        if constexpr (OUT_F32)
          ((float*)g.C)[(size_t)row * N + col] = v;
        else
          ((unsigned short*)g.C)[(size_t)row * N + col] = f2bf(v);
      }
    }
  }
}

// ---------------------------------------------------------------------------
// Causal flash attention (frozen — r7 form, ~71us). Q pre-scaled by
// 0.125*log2(e); NO-MAX exp2 softmax; l via ones-MFMA. Single-buffered
// K/V^T, two barriers/step, T14 reg prefetch. (512,8): measured 52 VGPR.
// ---------------------------------------------------------------------------
__global__ __launch_bounds__(512, 8) void attn_kernel(const unsigned short* __restrict__ Qp,
                                                      const unsigned short* __restrict__ Kp,
                                                      const unsigned short* __restrict__ Vt,
                                                      unsigned short* __restrict__ Op) {
  __shared__ unsigned short k_lds[64][76];
  __shared__ unsigned short vt_lds[64][76];   // [d][k]
  __shared__ unsigned short p_lds[8][16][76];

  int tid = threadIdx.x;
  int w = tid >> 6, lane = tid & 63;
  int l15 = lane & 15, lg = lane >> 4;

  int bid = blockIdx.x;                    // 0..511
  int swz = (bid & 7) * 64 + (bid >> 3);   // bijective (512 % 8 == 0)
  int pairIdx = swz & 7;                   // 0..7
  int bh = swz >> 3;                       // 0..63 (8 bh per XCD)
  int b = bh >> 4, h = bh & 15;

  const unsigned short* Kbase = Kp + (size_t)b * S_LEN * D_MODEL + h * DEPTH;
  const unsigned short* Vbase = Vt + (size_t)bh * DEPTH * S_LEN;

  bool stageV = (tid >= 256);
  int st = tid & 255;
  int r = st >> 2, cb = (st & 3) * 16;
  const unsigned short* srow = stageV ? (Vbase + (size_t)r * S_LEN + cb)
                                      : (Kbase + (size_t)r * D_MODEL + cb);
  const size_t sstep = stageV ? 64 : (size_t)64 * D_MODEL;

  bf16x8 ones;
#pragma unroll
  for (int e = 0; e < 8; ++e) ones[e] = (short)0x3F80;

  for (int half = 0; half < 2; ++half) {
    int t = (half == 0) ? pairIdx : (15 - pairIdx);
    int q0 = t * 128;
    int nkv = 2 * t + 2;
    int q0w = q0 + w * 16;

    const unsigned short* qp =
        Qp + ((size_t)(b * S_LEN + q0 + w * 16 + l15)) * D_MODEL + h * DEPTH;
    bf16x8 qf0 = *(const bf16x8*)(qp + lg * 8);
    bf16x8 qf1 = *(const bf16x8*)(qp + 32 + lg * 8);

    f32x4 acc_l = (f32x4){0.f, 0.f, 0.f, 0.f};
    f32x4 acc_o[4];
#pragma unroll
    for (int dd = 0; dd < 4; ++dd) acc_o[dd] = (f32x4){0.f, 0.f, 0.f, 0.f};

    // prologue: load tile 0 into regs
    const unsigned short* sptr = srow;
    us8 s0 = *(const us8*)sptr;
    us8 s1 = *(const us8*)(sptr + 8);
    sptr += sstep;

    for (int kb = 0; kb < nkv; ++kb) {
      int k0 = kb * 64;
      __syncthreads();  // readers of tile kb-1 (or prior half) done
      if (stageV) {
        *(us8*)&vt_lds[r][cb] = s0;
        *(us8*)&vt_lds[r][cb + 8] = s1;
      } else {
        *(us8*)&k_lds[r][cb] = s0;
        *(us8*)&k_lds[r][cb + 8] = s1;
      }
      __syncthreads();  // tile kb visible
      bool more = (kb + 1) < nkv;
      if (more) {
        s0 = *(const us8*)sptr;        // issue next tile's loads early (T14);
        s1 = *(const us8*)(sptr + 8);  // latency hides under compute below
        sptr += sstep;
      }

      bool full_masked = (k0 > q0w + 15);
      if (!full_masked) {
        f32x4 s[4];
#pragma unroll
        for (int nf = 0; nf < 4; ++nf) s[nf] = (f32x4){0.f, 0.f, 0.f, 0.f};
        __builtin_amdgcn_s_setprio(1);
#pragma unroll
        for (int nf = 0; nf < 4; ++nf) {
          bf16x8 kf0 = *(const bf16x8*)&k_lds[nf * 16 + l15][lg * 8];
          bf16x8 kf1 = *(const bf16x8*)&k_lds[nf * 16 + l15][32 + lg * 8];
          s[nf] = __builtin_amdgcn_mfma_f32_16x16x32_bf16(qf0, kf0, s[nf], 0, 0, 0);
          s[nf] = __builtin_amdgcn_mfma_f32_16x16x32_bf16(qf1, kf1, s[nf], 0, 0, 0);
        }
        __builtin_amdgcn_s_setprio(0);

        bool diag = (k0 + 63 > q0w);
        if (diag) {
#pragma unroll
          for (int nf = 0; nf < 4; ++nf)
#pragma unroll
            for (int rr = 0; rr < 4; ++rr) {
              int qrow = q0w + lg * 4 + rr;
              int kcol = k0 + nf * 16 + l15;
              float x = (kcol > qrow) ? -1e10f : s[nf][rr];
              float p = __builtin_amdgcn_exp2f(x);
              p_lds[w][lg * 4 + rr][nf * 16 + l15] =
                  (unsigned short)(__builtin_bit_cast(unsigned int, p) >> 16);
            }
        } else {
#pragma unroll
          for (int nf = 0; nf < 4; ++nf)
#pragma unroll
            for (int rr = 0; rr < 4; ++rr) {
              float p = __builtin_amdgcn_exp2f(s[nf][rr]);
              p_lds[w][lg * 4 + rr][nf * 16 + l15] =
                  (unsigned short)(__builtin_bit_cast(unsigned int, p) >> 16);
            }
        }

        __builtin_amdgcn_s_setprio(1);
#pragma unroll
        for (int kk = 0; kk < 2; ++kk) {
          bf16x8 pf = *(const bf16x8*)&p_lds[w][l15][kk * 32 + lg * 8];
          acc_l = __builtin_amdgcn_mfma_f32_16x16x32_bf16(pf, ones, acc_l, 0, 0, 0);
#pragma unroll
          for (int dd = 0; dd < 4; ++dd) {
            bf16x8 vf = *(const bf16x8*)&vt_lds[dd * 16 + l15][kk * 32 + lg * 8];
            acc_o[dd] = __builtin_amdgcn_mfma_f32_16x16x32_bf16(pf, vf, acc_o[dd], 0, 0, 0);
          }
        }
        __builtin_amdgcn_s_setprio(0);
      }
    }

#pragma unroll
    for (int rr = 0; rr < 4; ++rr) {
      float inv = 1.0f / acc_l[rr];
      int qrow = q0 + w * 16 + lg * 4 + rr;
      unsigned short* op = Op + ((size_t)(b * S_LEN + qrow)) * D_MODEL + h * DEPTH;
#pragma unroll
      for (int dd = 0; dd < 4; ++dd)
        op[dd * 16 + l15] = f2bf(acc_o[dd][rr] * inv);
    }
  }
}

// ---------------------------------------------------------------------------
extern "C" void kernel_launch(void* const* d_in, const int* in_sizes, int n_in,
                              void* d_out, int out_size, void* d_ws, size_t ws_size,
                              hipStream_t stream) {
  const float* q  = (const float*)d_in[0];
  const float* v  = (const float*)d_in[1];
  const float* k  = (const float*)d_in[2];
  const float* Wq = (const float*)d_in[3];
  const float* bq = (const float*)d_in[4];
  const float* Wk = (const float*)d_in[5];
  const float* bk = (const float*)d_in[6];
  const float* Wv = (const float*)d_in[7];
  const float* bv = (const float*)d_in[8];
  const float* Wo = (const float*)d_in[9];
  const float* bo = (const float*)d_in[10];

  char* ws = (char*)d_ws;
  const size_t WSZ = (size_t)D_MODEL * D_MODEL * 2;        // 2 MB per weight
  const size_t XSZ = (size_t)BATCH * S_LEN * D_MODEL * 2;  // 16 MB per activation
  unsigned short* Wqt = (unsigned short*)(ws);
  unsigned short* Wkt = (unsigned short*)(ws + WSZ);
  unsigned short* Wvt = (unsigned short*)(ws + 2 * WSZ);
  unsigned short* Wot = (unsigned short*)(ws + 3 * WSZ);
  unsigned short* Qp  = (unsigned short*)(ws + 4 * WSZ);
  unsigned short* Kp  = (unsigned short*)(ws + 4 * WSZ + XSZ);
  unsigned short* Vp  = (unsigned short*)(ws + 4 * WSZ + 2 * XSZ);
  unsigned short* Vtp = (unsigned short*)(ws + 4 * WSZ + 3 * XSZ);
  unsigned short* AO  = Vp;  // alias: Vp fully consumed by transpose_v before attn writes AO

  const float SCL = 0.125f * 1.4426950408889634f;
  const int M = BATCH * S_LEN;

  TCArgs tc{};
  tc.W[0] = Wq;  tc.Wt[0] = Wqt;  tc.scale[0] = SCL;
  tc.W[1] = Wk;  tc.Wt[1] = Wkt;  tc.scale[1] = 1.0f;
  tc.W[2] = Wv;  tc.Wt[2] = Wvt;  tc.scale[2] = 1.0f;
  tc.W[3] = Wo;  tc.Wt[3] = Wot;  tc.scale[3] = 1.0f;
  hipLaunchKernelGGL(transpose_cast4, dim3(D_MODEL / 32, D_MODEL / 32, 4), dim3(32, 8),
                     0, stream, tc, D_MODEL);

  GemmArgs qkv{};
  qkv.s[0] = GemmSlice{(const void*)q, Wqt, bq, (void*)Qp, SCL};
  qkv.s[1] = GemmSlice{(const void*)k, Wkt, bk, (void*)Kp, 1.0f};
  qkv.s[2] = GemmSlice{(const void*)v, Wvt, bv, (void*)Vp, 1.0f};
  hipLaunchKernelGGL((gemm_bt<true, false>), dim3(M / 128, 24), dim3(256), 0, stream,
                     qkv, M, D_MODEL, D_MODEL);

  hipLaunchKernelGGL(transpose_v, dim3(S_LEN / 64, BATCH * N_HEADS), dim3(256), 0, stream,
                     Vp, Vtp);

  hipLaunchKernelGGL(attn_kernel, dim3(512), dim3(512), 0, stream, Qp, Kp, Vtp, AO);

  GemmArgs ao{};
  ao.s[0] = GemmSlice{(const void*)AO, Wot, bo, d_out, 1.0f};
  hipLaunchKernelGGL((gemm_bt<false, true>), dim3(M / 128, 8), dim3(256), 0, stream,
                     ao, M, D_MODEL, D_MODEL);
}

// Round 10
// 178.421 us; speedup vs baseline: 2.5811x; 1.1845x over previous
//
#include <hip/hip_runtime.h>
#include <hip/hip_bf16.h>
#include <cstdint>
#include <cstddef>

#define S_LEN 2048
#define D_MODEL 1024
#define N_HEADS 16
#define DEPTH 64
#define BATCH 4

#define GLOBAL_AS __attribute__((address_space(1)))
#define LDS_AS __attribute__((address_space(3)))

typedef __attribute__((ext_vector_type(4))) float f32x4;
typedef __attribute__((ext_vector_type(8))) short bf16x8;
typedef __attribute__((ext_vector_type(4))) unsigned short us4;
typedef __attribute__((ext_vector_type(8))) unsigned short us8;

__device__ __forceinline__ unsigned short f2bf(float f) {
  unsigned int u = __builtin_bit_cast(unsigned int, f);
  u += 0x7FFFu + ((u >> 16) & 1u);   // round-to-nearest-even
  return (unsigned short)(u >> 16);
}

// HW cast (compiler emits v_cvt_pk_bf16_f32 pairs)
__device__ __forceinline__ unsigned short f2bf_hw(float f) {
  return __builtin_bit_cast(unsigned short, __float2bfloat16(f));
}

// ---------------------------------------------------------------------------
// Fused weight transpose + scale + fp32 -> bf16 cast for all 4 weights:
// Wt[n][k] = W[k][n] * scale.  grid.z selects the weight.
// ---------------------------------------------------------------------------
struct TCArgs {
  const float* W[4];
  unsigned short* Wt[4];
  float scale[4];
};

__global__ __launch_bounds__(256) void transpose_cast4(TCArgs a, int N) {
  __shared__ float tile[32][33];
  int z = blockIdx.z;
  const float* W = a.W[z];
  unsigned short* Wt = a.Wt[z];
  float scale = a.scale[z];
  int bx = blockIdx.x * 32;  // n-range
  int by = blockIdx.y * 32;  // k-range
  int tx = threadIdx.x, ty = threadIdx.y;  // 32 x 8
#pragma unroll
  for (int i = 0; i < 4; ++i)
    tile[ty + i * 8][tx] = W[(size_t)(by + ty + i * 8) * N + bx + tx];
  __syncthreads();
#pragma unroll
  for (int i = 0; i < 4; ++i)
    Wt[(size_t)(bx + ty + i * 8) * N + by + tx] = f2bf(tile[tx][ty + i * 8] * scale);
}

// ---------------------------------------------------------------------------
// Per-head V transpose: Vp [B,S,D] bf16 -> Vt [B*H][DEPTH][S] bf16
// ---------------------------------------------------------------------------
__global__ __launch_bounds__(256) void transpose_v(const unsigned short* __restrict__ Vp,
                                                   unsigned short* __restrict__ Vt) {
  __shared__ unsigned short tile[64][72];  // tile[d][s_local]
  int tid = threadIdx.x;
  int sb = blockIdx.x;   // 0..31
  int bh = blockIdx.y;   // 0..63
  int b = bh >> 4, h = bh & 15;
  int s0 = sb * 64;
#pragma unroll
  for (int rep = 0; rep < 2; ++rep) {
    int idx = rep * 256 + tid;
    int r = idx >> 3, c8 = idx & 7;
    us8 v = *(const us8*)(Vp + (size_t)(b * S_LEN + s0 + r) * D_MODEL + h * DEPTH + c8 * 8);
#pragma unroll
    for (int e = 0; e < 8; ++e) tile[c8 * 8 + e][r] = v[e];
  }
  __syncthreads();
#pragma unroll
  for (int rep = 0; rep < 2; ++rep) {
    int idx = rep * 256 + tid;
    int d = idx >> 3, c8 = idx & 7;
    us8 v = *(const us8*)&tile[d][c8 * 8];
    *(us8*)(Vt + ((size_t)(bh * DEPTH + d)) * S_LEN + s0 + c8 * 8) = v;
  }
}

// ---------------------------------------------------------------------------
// GEMM:  C[M][N] = A[M][K] @ Bt[N][K]^T + bias*bscale
// Reg-staged 2-barrier K-loop + T14 register prefetch of tile k+1 for BOTH
// operands (r8: QKV ~65-70us, near the 128^2-structure ceiling). bf16-A
// path (AO): A via glds, B reg-prefetched. No min-waves bound anywhere
// (r6/r8 lesson: min-waves bounds invite silent spill catastrophes).
// ---------------------------------------------------------------------------
struct GemmSlice {
  const void* A;
  const unsigned short* Bt;
  const float* bias;
  void* C;
  float bscale;
};
struct GemmArgs {
  GemmSlice s[3];
};

template <bool A_IS_F32, bool OUT_F32>
__global__ __launch_bounds__(256) void gemm_bt(GemmArgs args, int M, int N, int K) {
  constexpr int ASTR = A_IS_F32 ? 72 : 64;
  __shared__ unsigned short a_lds[128 * ASTR];
  __shared__ unsigned short b_lds[128 * 72];

  int slice = blockIdx.y >> 3;
  int nj = blockIdx.y & 7;
  const GemmSlice& g = args.s[slice];
  const float* Af = (const float*)g.A;
  const unsigned short* Ah = (const unsigned short*)g.A;
  const unsigned short* Bt = g.Bt;

  int tid = threadIdx.x;
  int wave = tid >> 6, lane = tid & 63;
  int l15 = lane & 15, lg = lane >> 4;
  int wm = wave >> 1, wn = wave & 1;

  int row0 = blockIdx.x * 128;
  int col0 = nj * 128;

  f32x4 acc[4][4] = {};
  f32x4 av[8];  // in-flight A tile (fp32 path)
  us8 bv[4];    // in-flight B tile

  int ar = tid >> 4, ac4 = tid & 15;  // fp32-A staging coords
  int br = tid >> 3, bc8 = tid & 7;   // B staging coords

  auto loadA = [&](int k0) {
#pragma unroll
    for (int rep = 0; rep < 8; ++rep)
      av[rep] = *(const f32x4*)(Af + (size_t)(row0 + rep * 16 + ar) * K + k0 + ac4 * 4);
  };
  auto writeA = [&]() {
#pragma unroll
    for (int rep = 0; rep < 8; ++rep) {
      us4 h = {f2bf_hw(av[rep][0]), f2bf_hw(av[rep][1]),
               f2bf_hw(av[rep][2]), f2bf_hw(av[rep][3])};
      *(us4*)&a_lds[(rep * 16 + ar) * 72 + ac4 * 4] = h;
    }
  };
  auto loadB = [&](int k0) {
#pragma unroll
    for (int rep = 0; rep < 4; ++rep)
      bv[rep] = *(const us8*)(Bt + (size_t)(col0 + rep * 32 + br) * K + k0 + bc8 * 8);
  };
  auto writeB = [&]() {
#pragma unroll
    for (int rep = 0; rep < 4; ++rep)
      *(us8*)&b_lds[(rep * 32 + br) * 72 + bc8 * 8] = bv[rep];
  };
  auto issueA = [&](int k0) {  // bf16-A via glds, swizzled source
#pragma unroll
    for (int rep = 0; rep < 4; ++rep) {
      int chunk = (wave * 4 + rep) * 64 + lane;
      int row = chunk >> 3;
      int c8 = (chunk & 7) ^ (row & 7);
      __builtin_amdgcn_global_load_lds(
          (const GLOBAL_AS void*)(Ah + (size_t)(row0 + row) * K + k0 + c8 * 8),
          (LDS_AS void*)(&a_lds[chunk * 8]), 16, 0, 0);
    }
  };
  auto compute = [&]() {
#pragma unroll
    for (int kk = 0; kk < 2; ++kk) {
      bf16x8 af[4], bfr[4];
#pragma unroll
      for (int ii = 0; ii < 4; ++ii) {
        int row = wm * 64 + ii * 16 + l15;
        if constexpr (A_IS_F32)
          af[ii] = *(const bf16x8*)&a_lds[row * 72 + kk * 32 + lg * 8];
        else
          af[ii] = *(const bf16x8*)&a_lds[row * 64 + (((kk * 4 + lg) ^ (l15 & 7)) * 8)];
      }
#pragma unroll
      for (int jj = 0; jj < 4; ++jj) {
        int row = wn * 64 + jj * 16 + l15;
        bfr[jj] = *(const bf16x8*)&b_lds[row * 72 + kk * 32 + lg * 8];
      }
#pragma unroll
      for (int ii = 0; ii < 4; ++ii)
#pragma unroll
        for (int jj = 0; jj < 4; ++jj)
          acc[ii][jj] = __builtin_amdgcn_mfma_f32_16x16x32_bf16(af[ii], bfr[jj], acc[ii][jj], 0, 0, 0);
    }
  };

  int nk = K >> 6;
  loadB(0);
  if constexpr (A_IS_F32) loadA(0);

  for (int ki = 0; ki < nk; ++ki) {
    __syncthreads();  // readers of previous tile done
    writeB();
    if constexpr (A_IS_F32)
      writeA();
    else
      issueA(ki * 64);
    __syncthreads();  // tile visible (drains lgkm + vmcnt)
    if (ki + 1 < nk) {
      loadB((ki + 1) * 64);                    // prefetch next tile's regs —
      if constexpr (A_IS_F32) loadA((ki + 1) * 64);  // latency hides under MFMAs
    }
    compute();
  }

  // ---- epilogue ----
#pragma unroll
  for (int ii = 0; ii < 4; ++ii) {
#pragma unroll
    for (int jj = 0; jj < 4; ++jj) {
      int col = col0 + wn * 64 + jj * 16 + l15;
      float bv2 = g.bias[col] * g.bscale;
#pragma unroll
      for (int r = 0; r < 4; ++r) {
        int row = row0 + wm * 64 + ii * 16 + lg * 4 + r;
        float v = acc[ii][jj][r] + bv2;
        if constexpr (OUT_F32)
          ((float*)g.C)[(size_t)row * N + col] = v;
        else
          ((unsigned short*)g.C)[(size_t)row * N + col] = f2bf(v);
      }
    }
  }
}

// ---------------------------------------------------------------------------
// Causal flash attention (body frozen, ~71us proven). Q pre-scaled by
// 0.125*log2(e); NO-MAX exp2 softmax; l via ones-MFMA. Single-buffered
// K/V^T, two barriers/step, T14 reg prefetch.
// NO min-waves bound: r8's (512,8) + co-compile regalloc perturbation
// (rule #19) squeezed VGPR 52->32 and spilled (WRITE 89MB, 107us). Plain
// bound can't spill; worst case 2 blocks/CU = the measured-71us point.
// ---------------------------------------------------------------------------
__global__ __launch_bounds__(512) void attn_kernel(const unsigned short* __restrict__ Qp,
                                                   const unsigned short* __restrict__ Kp,
                                                   const unsigned short* __restrict__ Vt,
                                                   unsigned short* __restrict__ Op) {
  __shared__ unsigned short k_lds[64][76];
  __shared__ unsigned short vt_lds[64][76];   // [d][k]
  __shared__ unsigned short p_lds[8][16][76];

  int tid = threadIdx.x;
  int w = tid >> 6, lane = tid & 63;
  int l15 = lane & 15, lg = lane >> 4;

  int bid = blockIdx.x;                    // 0..511
  int swz = (bid & 7) * 64 + (bid >> 3);   // bijective (512 % 8 == 0)
  int pairIdx = swz & 7;                   // 0..7
  int bh = swz >> 3;                       // 0..63 (8 bh per XCD)
  int b = bh >> 4, h = bh & 15;

  const unsigned short* Kbase = Kp + (size_t)b * S_LEN * D_MODEL + h * DEPTH;
  const unsigned short* Vbase = Vt + (size_t)bh * DEPTH * S_LEN;

  bool stageV = (tid >= 256);
  int st = tid & 255;
  int r = st >> 2, cb = (st & 3) * 16;
  const unsigned short* srow = stageV ? (Vbase + (size_t)r * S_LEN + cb)
                                      : (Kbase + (size_t)r * D_MODEL + cb);
  const size_t sstep = stageV ? 64 : (size_t)64 * D_MODEL;

  bf16x8 ones;
#pragma unroll
  for (int e = 0; e < 8; ++e) ones[e] = (short)0x3F80;

  for (int half = 0; half < 2; ++half) {
    int t = (half == 0) ? pairIdx : (15 - pairIdx);
    int q0 = t * 128;
    int nkv = 2 * t + 2;
    int q0w = q0 + w * 16;

    const unsigned short* qp =
        Qp + ((size_t)(b * S_LEN + q0 + w * 16 + l15)) * D_MODEL + h * DEPTH;
    bf16x8 qf0 = *(const bf16x8*)(qp + lg * 8);
    bf16x8 qf1 = *(const bf16x8*)(qp + 32 + lg * 8);

    f32x4 acc_l = (f32x4){0.f, 0.f, 0.f, 0.f};
    f32x4 acc_o[4];
#pragma unroll
    for (int dd = 0; dd < 4; ++dd) acc_o[dd] = (f32x4){0.f, 0.f, 0.f, 0.f};

    // prologue: load tile 0 into regs
    const unsigned short* sptr = srow;
    us8 s0 = *(const us8*)sptr;
    us8 s1 = *(const us8*)(sptr + 8);
    sptr += sstep;

    for (int kb = 0; kb < nkv; ++kb) {
      int k0 = kb * 64;
      __syncthreads();  // readers of tile kb-1 (or prior half) done
      if (stageV) {
        *(us8*)&vt_lds[r][cb] = s0;
        *(us8*)&vt_lds[r][cb + 8] = s1;
      } else {
        *(us8*)&k_lds[r][cb] = s0;
        *(us8*)&k_lds[r][cb + 8] = s1;
      }
      __syncthreads();  // tile kb visible
      bool more = (kb + 1) < nkv;
      if (more) {
        s0 = *(const us8*)sptr;        // issue next tile's loads early (T14);
        s1 = *(const us8*)(sptr + 8);  // latency hides under compute below
        sptr += sstep;
      }

      bool full_masked = (k0 > q0w + 15);
      if (!full_masked) {
        f32x4 s[4];
#pragma unroll
        for (int nf = 0; nf < 4; ++nf) s[nf] = (f32x4){0.f, 0.f, 0.f, 0.f};
        __builtin_amdgcn_s_setprio(1);
#pragma unroll
        for (int nf = 0; nf < 4; ++nf) {
          bf16x8 kf0 = *(const bf16x8*)&k_lds[nf * 16 + l15][lg * 8];
          bf16x8 kf1 = *(const bf16x8*)&k_lds[nf * 16 + l15][32 + lg * 8];
          s[nf] = __builtin_amdgcn_mfma_f32_16x16x32_bf16(qf0, kf0, s[nf], 0, 0, 0);
          s[nf] = __builtin_amdgcn_mfma_f32_16x16x32_bf16(qf1, kf1, s[nf], 0, 0, 0);
        }
        __builtin_amdgcn_s_setprio(0);

        bool diag = (k0 + 63 > q0w);
        if (diag) {
#pragma unroll
          for (int nf = 0; nf < 4; ++nf)
#pragma unroll
            for (int rr = 0; rr < 4; ++rr) {
              int qrow = q0w + lg * 4 + rr;
              int kcol = k0 + nf * 16 + l15;
              float x = (kcol > qrow) ? -1e10f : s[nf][rr];
              float p = __builtin_amdgcn_exp2f(x);
              p_lds[w][lg * 4 + rr][nf * 16 + l15] =
                  (unsigned short)(__builtin_bit_cast(unsigned int, p) >> 16);
            }
        } else {
#pragma unroll
          for (int nf = 0; nf < 4; ++nf)
#pragma unroll
            for (int rr = 0; rr < 4; ++rr) {
              float p = __builtin_amdgcn_exp2f(s[nf][rr]);
              p_lds[w][lg * 4 + rr][nf * 16 + l15] =
                  (unsigned short)(__builtin_bit_cast(unsigned int, p) >> 16);
            }
        }

        __builtin_amdgcn_s_setprio(1);
#pragma unroll
        for (int kk = 0; kk < 2; ++kk) {
          bf16x8 pf = *(const bf16x8*)&p_lds[w][l15][kk * 32 + lg * 8];
          acc_l = __builtin_amdgcn_mfma_f32_16x16x32_bf16(pf, ones, acc_l, 0, 0, 0);
#pragma unroll
          for (int dd = 0; dd < 4; ++dd) {
            bf16x8 vf = *(const bf16x8*)&vt_lds[dd * 16 + l15][kk * 32 + lg * 8];
            acc_o[dd] = __builtin_amdgcn_mfma_f32_16x16x32_bf16(pf, vf, acc_o[dd], 0, 0, 0);
          }
        }
        __builtin_amdgcn_s_setprio(0);
      }
    }

#pragma unroll
    for (int rr = 0; rr < 4; ++rr) {
      float inv = 1.0f / acc_l[rr];
      int qrow = q0 + w * 16 + lg * 4 + rr;
      unsigned short* op = Op + ((size_t)(b * S_LEN + qrow)) * D_MODEL + h * DEPTH;
#pragma unroll
      for (int dd = 0; dd < 4; ++dd)
        op[dd * 16 + l15] = f2bf(acc_o[dd][rr] * inv);
    }
  }
}

// ---------------------------------------------------------------------------
extern "C" void kernel_launch(void* const* d_in, const int* in_sizes, int n_in,
                              void* d_out, int out_size, void* d_ws, size_t ws_size,
                              hipStream_t stream) {
  const float* q  = (const float*)d_in[0];
  const float* v  = (const float*)d_in[1];
  const float* k  = (const float*)d_in[2];
  const float* Wq = (const float*)d_in[3];
  const float* bq = (const float*)d_in[4];
  const float* Wk = (const float*)d_in[5];
  const float* bk = (const float*)d_in[6];
  const float* Wv = (const float*)d_in[7];
  const float* bv = (const float*)d_in[8];
  const float* Wo = (const float*)d_in[9];
  const float* bo = (const float*)d_in[10];

  char* ws = (char*)d_ws;
  const size_t WSZ = (size_t)D_MODEL * D_MODEL * 2;        // 2 MB per weight
  const size_t XSZ = (size_t)BATCH * S_LEN * D_MODEL * 2;  // 16 MB per activation
  unsigned short* Wqt = (unsigned short*)(ws);
  unsigned short* Wkt = (unsigned short*)(ws + WSZ);
  unsigned short* Wvt = (unsigned short*)(ws + 2 * WSZ);
  unsigned short* Wot = (unsigned short*)(ws + 3 * WSZ);
  unsigned short* Qp  = (unsigned short*)(ws + 4 * WSZ);
  unsigned short* Kp  = (unsigned short*)(ws + 4 * WSZ + XSZ);
  unsigned short* Vp  = (unsigned short*)(ws + 4 * WSZ + 2 * XSZ);
  unsigned short* Vtp = (unsigned short*)(ws + 4 * WSZ + 3 * XSZ);
  unsigned short* AO  = Vp;  // alias: Vp fully consumed by transpose_v before attn writes AO

  const float SCL = 0.125f * 1.4426950408889634f;
  const int M = BATCH * S_LEN;

  TCArgs tc{};
  tc.W[0] = Wq;  tc.Wt[0] = Wqt;  tc.scale[0] = SCL;
  tc.W[1] = Wk;  tc.Wt[1] = Wkt;  tc.scale[1] = 1.0f;
  tc.W[2] = Wv;  tc.Wt[2] = Wvt;  tc.scale[2] = 1.0f;
  tc.W[3] = Wo;  tc.Wt[3] = Wot;  tc.scale[3] = 1.0f;
  hipLaunchKernelGGL(transpose_cast4, dim3(D_MODEL / 32, D_MODEL / 32, 4), dim3(32, 8),
                     0, stream, tc, D_MODEL);

  GemmArgs qkv{};
  qkv.s[0] = GemmSlice{(const void*)q, Wqt, bq, (void*)Qp, SCL};
  qkv.s[1] = GemmSlice{(const void*)k, Wkt, bk, (void*)Kp, 1.0f};
  qkv.s[2] = GemmSlice{(const void*)v, Wvt, bv, (void*)Vp, 1.0f};
  hipLaunchKernelGGL((gemm_bt<true, false>), dim3(M / 128, 24), dim3(256), 0, stream,
                     qkv, M, D_MODEL, D_MODEL);

  hipLaunchKernelGGL(transpose_v, dim3(S_LEN / 64, BATCH * N_HEADS), dim3(256), 0, stream,
                     Vp, Vtp);

  hipLaunchKernelGGL(attn_kernel, dim3(512), dim3(512), 0, stream, Qp, Kp, Vtp, AO);

  GemmArgs ao{};
  ao.s[0] = GemmSlice{(const void*)AO, Wot, bo, d_out, 1.0f};
  hipLaunchKernelGGL((gemm_bt<false, true>), dim3(M / 128, 8), dim3(256), 0, stream,
                     ao, M, D_MODEL, D_MODEL);
}